// Round 1
// baseline (3109.448 us; speedup 1.0000x reference)
//
#include <hip/hip_runtime.h>
#include <math.h>

// Problem constants (fixed by the reference)
#define PPP 20000   // paths
#define TT  30      // max timesteps
#define SS  1000    // samples
#define PB  32      // paths per LSTM block
#define KT  8       // k-tile rows staged in LDS

// ---------------- length bucketing (counting sort by path length) -----------

__global__ void k_zero(int* bins) {
    if (threadIdx.x < 32) bins[threadIdx.x] = 0;
}

__global__ void k_hist(const int* __restrict__ len, int* __restrict__ bins) {
    int p = blockIdx.x * 256 + threadIdx.x;
    if (p < PPP) atomicAdd(&bins[len[p] - 1], 1);
}

__global__ void k_scan(const int* __restrict__ bins, int* __restrict__ cur) {
    if (threadIdx.x == 0 && blockIdx.x == 0) {
        int ofs = 0;
        for (int l = 0; l < TT; l++) { cur[l] = ofs; ofs += bins[l]; }
    }
}

__global__ void k_scatter(const int* __restrict__ len, int* __restrict__ cur,
                          int* __restrict__ order) {
    int p = blockIdx.x * 256 + threadIdx.x;
    if (p < PPP) {
        int pos = atomicAdd(&cur[len[p] - 1], 1);
        order[pos] = p;
    }
}

// ---------------- LSTM (both directions via blockIdx.y) --------------------
// Block: 32 paths, 256 threads. Thread (tc = tid/4 in [0,64), tp = tid%4):
//   owns 8 paths (tp*8..) x 2 elements (tc*2..) x 4 gates = 64 accumulators.
// LDS: XT[128][32] (x_t transposed), HT[128][32] (h transposed, persistent),
//      Wt[8][512] (k-tile of W or U). c-state lives in registers.

__device__ __forceinline__ float fsigmoid(float x) {
    return 1.f / (1.f + __expf(-x));
}
__device__ __forceinline__ float ftanh(float x) {
    return 2.f / (1.f + __expf(-2.f * x)) - 1.f;
}

__global__ __launch_bounds__(256, 2) void lstm_kernel(
    const float* __restrict__ emb,
    const float* __restrict__ Wf, const float* __restrict__ Uf, const float* __restrict__ bf,
    const float* __restrict__ Wb, const float* __restrict__ Ub, const float* __restrict__ bb,
    const int* __restrict__ path_elements, const int* __restrict__ path_lengths,
    const int* __restrict__ order,
    float* __restrict__ h_out)   // [2][P][128]
{
    const int dir = blockIdx.y;
    const float* W    = dir ? Wb : Wf;
    const float* U    = dir ? Ub : Uf;
    const float* bias = dir ? bb : bf;

    __shared__ float XT[128][PB];
    __shared__ float HT[128][PB];
    __shared__ float Wt[KT][512];
    __shared__ int s_pid[PB];
    __shared__ int s_len[PB];

    const int tid = threadIdx.x;
    const int tc = tid >> 2;       // 0..63  element-pair group
    const int tp = tid & 3;        // 0..3   path group (8 paths)
    const int baseP = tp * 8;
    const int e0 = tc * 2;

    if (tid < PB) {
        int pid = order[blockIdx.x * PB + tid];
        s_pid[tid] = pid;
        s_len[tid] = path_lengths[pid];
    }
    for (int i = tid; i < 128 * PB; i += 256) ((float*)HT)[i] = 0.f;
    __syncthreads();

    int maxLen = 1;
    for (int i = 0; i < PB; i++) maxLen = max(maxLen, s_len[i]);

    float c[2][8];
#pragma unroll
    for (int e = 0; e < 2; e++)
#pragma unroll
        for (int p = 0; p < 8; p++) c[e][p] = 0.f;

    // bias registers per owned column
    float bz[4][2];
#pragma unroll
    for (int g = 0; g < 4; g++) {
        bz[g][0] = bias[g * 128 + e0];
        bz[g][1] = bias[g * 128 + e0 + 1];
    }

    const int pgath = tid >> 3;    // 0..31 path for x-gather
    const int chg   = tid & 7;     // 0..7 chunk

    for (int step = 0; step < maxLen; step++) {
        const int t = dir ? (maxLen - 1 - step) : step;

        // stage x_t transposed into XT
        {
            int tok = path_elements[s_pid[pgath] * TT + t];
            const float4* srow = (const float4*)(emb + (size_t)tok * 128);
#pragma unroll
            for (int j = 0; j < 4; j++) {
                float4 v = srow[j * 8 + chg];
                int k = (j * 8 + chg) * 4;
                XT[k + 0][pgath] = v.x;
                XT[k + 1][pgath] = v.y;
                XT[k + 2][pgath] = v.z;
                XT[k + 3][pgath] = v.w;
            }
        }

        float acc[4][2][8];
#pragma unroll
        for (int g = 0; g < 4; g++)
#pragma unroll
            for (int e = 0; e < 2; e++)
#pragma unroll
                for (int p = 0; p < 8; p++) acc[g][e][p] = bz[g][e];

        // 32 k-tiles: tiles 0..15 -> W with XT, 16..31 -> U with HT
        for (int kt = 0; kt < 32; kt++) {
            const float* srcmat = (kt < 16) ? W : U;
            const int krow0 = (kt & 15) * KT;
            // stage Wt[8][512]
#pragma unroll
            for (int j = 0; j < 4; j++) {
                int idx = j * 1024 + tid * 4;
                *(float4*)(&Wt[0][0] + idx) =
                    *(const float4*)(srcmat + krow0 * 512 + idx);
            }
            __syncthreads();

            const float (*SRC)[PB] = (kt < 16) ? XT : HT;
#pragma unroll
            for (int kk = 0; kk < KT; kk++) {
                const int krow = krow0 + kk;
                float4 a0 = *(const float4*)&SRC[krow][baseP];
                float4 a1 = *(const float4*)&SRC[krow][baseP + 4];
                float a[8] = {a0.x, a0.y, a0.z, a0.w, a1.x, a1.y, a1.z, a1.w};
                float w[4][2];
#pragma unroll
                for (int g = 0; g < 4; g++) {
                    float2 wv = *(const float2*)&Wt[kk][g * 128 + e0];
                    w[g][0] = wv.x; w[g][1] = wv.y;
                }
#pragma unroll
                for (int g = 0; g < 4; g++)
#pragma unroll
                    for (int e = 0; e < 2; e++)
#pragma unroll
                        for (int p = 0; p < 8; p++)
                            acc[g][e][p] = fmaf(a[p], w[g][e], acc[g][e][p]);
            }
            __syncthreads();
        }

        // gating (fully in registers; c persistent, h -> LDS)
#pragma unroll
        for (int p = 0; p < 8; p++) {
            bool valid = t < s_len[baseP + p];
#pragma unroll
            for (int e = 0; e < 2; e++) {
                float zi = acc[0][e][p];
                float zf = acc[1][e][p];
                float zg = acc[2][e][p];
                float zo = acc[3][e][p];
                float ig = fsigmoid(zi);
                float fg = fsigmoid(zf);
                float gg = ftanh(zg);
                float og = fsigmoid(zo);
                float cn = fg * c[e][p] + ig * gg;
                float hn = og * ftanh(cn);
                if (valid) {
                    c[e][p] = cn;
                    HT[e0 + e][baseP + p] = hn;
                }
            }
        }
        __syncthreads();
    }

    // write final h
    {
        int pid = s_pid[pgath];
        float* dst = h_out + ((size_t)dir * PPP + pid) * 128;
#pragma unroll
        for (int j = 0; j < 16; j++) dst[chg * 16 + j] = HT[chg * 16 + j][pgath];
    }
}

// ---------------- projection + attention scores ----------------------------
// full[p] = [leaf0(64) leaf1(64) h_f(128) h_b(128)] @ proj(384x128)
// scores[p] = full[p] . att
// 16 paths / block, 256 threads: thread (pp=tid/16, cg=tid%16) -> 8 cols.

__global__ __launch_bounds__(256) void proj_kernel(
    const float* __restrict__ leaf, const float* __restrict__ hbuf,
    const float* __restrict__ proj, const float* __restrict__ att,
    const int* __restrict__ leaf_idxs,
    float* __restrict__ full, float* __restrict__ scores)
{
    __shared__ float V[16][388];
    const int tid = threadIdx.x;
    const int p0 = blockIdx.x * 16;

    for (int idx = tid; idx < 16 * 96; idx += 256) {
        int p = idx / 96, off = idx % 96;
        const float* src;
        if (off < 16) {
            int l0 = leaf_idxs[(p0 + p) * 2 + 0];
            src = leaf + (size_t)l0 * 64 + off * 4;
        } else if (off < 32) {
            int l1 = leaf_idxs[(p0 + p) * 2 + 1];
            src = leaf + (size_t)l1 * 64 + (off - 16) * 4;
        } else if (off < 64) {
            src = hbuf + (size_t)(p0 + p) * 128 + (off - 32) * 4;
        } else {
            src = hbuf + ((size_t)PPP + p0 + p) * 128 + (off - 64) * 4;
        }
        *(float4*)&V[p][off * 4] = *(const float4*)src;
    }
    __syncthreads();

    const int pp = tid >> 4;
    const int cg = tid & 15;
    const int c0 = cg * 8;

    float acc[8];
#pragma unroll
    for (int j = 0; j < 8; j++) acc[j] = 0.f;

#pragma unroll 4
    for (int k = 0; k < 384; k++) {
        float a = V[pp][k];
        float4 w0 = *(const float4*)(proj + (size_t)k * 128 + c0);
        float4 w1 = *(const float4*)(proj + (size_t)k * 128 + c0 + 4);
        acc[0] = fmaf(a, w0.x, acc[0]);
        acc[1] = fmaf(a, w0.y, acc[1]);
        acc[2] = fmaf(a, w0.z, acc[2]);
        acc[3] = fmaf(a, w0.w, acc[3]);
        acc[4] = fmaf(a, w1.x, acc[4]);
        acc[5] = fmaf(a, w1.y, acc[5]);
        acc[6] = fmaf(a, w1.z, acc[6]);
        acc[7] = fmaf(a, w1.w, acc[7]);
    }

    float* fdst = full + (size_t)(p0 + pp) * 128 + c0;
    *(float4*)fdst = make_float4(acc[0], acc[1], acc[2], acc[3]);
    *(float4*)(fdst + 4) = make_float4(acc[4], acc[5], acc[6], acc[7]);

    float sp = 0.f;
#pragma unroll
    for (int j = 0; j < 8; j++) sp += acc[j] * att[c0 + j];
#pragma unroll
    for (int off = 8; off > 0; off >>= 1) sp += __shfl_down(sp, off, 16);
    if (cg == 0) scores[p0 + pp] = sp;
}

// ---------------- segment softmax + weighted sum ---------------------------

__global__ __launch_bounds__(128) void seg_kernel(
    const float* __restrict__ scores, const float* __restrict__ full,
    const int* __restrict__ seg, float* __restrict__ out)
{
    const int s = blockIdx.x;
    const int tid = threadIdx.x;

    int lo = 0, hi = PPP;
    while (lo < hi) { int mid = (lo + hi) >> 1; if (seg[mid] < s) lo = mid + 1; else hi = mid; }
    const int start = lo;
    lo = start; hi = PPP;
    while (lo < hi) { int mid = (lo + hi) >> 1; if (seg[mid] < s + 1) lo = mid + 1; else hi = mid; }
    const int end = lo;

    if (start >= end) { out[(size_t)s * 128 + tid] = 0.f; return; }

    __shared__ float red[128];

    float mx = -1e30f;
    for (int i = start + tid; i < end; i += 128) mx = fmaxf(mx, scores[i]);
    red[tid] = mx; __syncthreads();
    for (int off = 64; off > 0; off >>= 1) {
        if (tid < off) red[tid] = fmaxf(red[tid], red[tid + off]);
        __syncthreads();
    }
    mx = red[0]; __syncthreads();

    float den = 0.f;
    for (int i = start + tid; i < end; i += 128) den += __expf(scores[i] - mx);
    red[tid] = den; __syncthreads();
    for (int off = 64; off > 0; off >>= 1) {
        if (tid < off) red[tid] += red[tid + off];
        __syncthreads();
    }
    den = red[0];

    float acc = 0.f;
    for (int i = start; i < end; i++)
        acc = fmaf(__expf(scores[i] - mx), full[(size_t)i * 128 + tid], acc);
    out[(size_t)s * 128 + tid] = acc / den;
}

// ---------------- launch ---------------------------------------------------

extern "C" void kernel_launch(void* const* d_in, const int* in_sizes, int n_in,
                              void* d_out, int out_size, void* d_ws, size_t ws_size,
                              hipStream_t stream) {
    (void)in_sizes; (void)n_in; (void)out_size; (void)ws_size;

    const float* leaf = (const float*)d_in[0];
    const float* emb  = (const float*)d_in[1];
    const float* Wf   = (const float*)d_in[2];
    const float* Uf   = (const float*)d_in[3];
    const float* bf   = (const float*)d_in[4];
    const float* Wb   = (const float*)d_in[5];
    const float* Ub   = (const float*)d_in[6];
    const float* bb   = (const float*)d_in[7];
    const float* proj = (const float*)d_in[8];
    const float* att  = (const float*)d_in[9];
    const int* path_elements = (const int*)d_in[10];
    const int* path_lengths  = (const int*)d_in[11];
    const int* leaf_idxs     = (const int*)d_in[12];
    const int* seg           = (const int*)d_in[13];
    float* out = (float*)d_out;

    char* ws = (char*)d_ws;
    int*   order  = (int*)ws;                                   // P ints
    int*   bins   = (int*)(ws + 80128);                         // 32 ints
    int*   cur    = (int*)(ws + 80384);                         // 32 ints
    float* hbuf   = (float*)(ws + 81920);                       // 2*P*128 f32
    float* full   = (float*)(ws + 81920 + 20480000);            // P*128 f32
    float* scores = (float*)(ws + 81920 + 20480000 + 10240000); // P f32

    k_zero<<<1, 64, 0, stream>>>(bins);
    k_hist<<<(PPP + 255) / 256, 256, 0, stream>>>(path_lengths, bins);
    k_scan<<<1, 64, 0, stream>>>(bins, cur);
    k_scatter<<<(PPP + 255) / 256, 256, 0, stream>>>(path_lengths, cur, order);

    dim3 g(PPP / PB, 2);
    lstm_kernel<<<g, 256, 0, stream>>>(emb, Wf, Uf, bf, Wb, Ub, bb,
                                       path_elements, path_lengths, order, hbuf);

    proj_kernel<<<PPP / 16, 256, 0, stream>>>(leaf, hbuf, proj, att, leaf_idxs,
                                              full, scores);

    seg_kernel<<<SS, 128, 0, stream>>>(scores, full, seg, out);
}

// Round 2
// 2295.987 us; speedup vs baseline: 1.3543x; 1.3543x over previous
//
#include <hip/hip_runtime.h>
#include <math.h>

#define PPP 20000   // paths
#define TT  30      // max timesteps
#define SS  1000    // samples
#define VNT 10000   // non-terminal vocab
#define PB  32      // paths per LSTM block

// ---------------- length bucketing (counting sort by path length) -----------

__global__ void k_zero(int* bins) {
    if (threadIdx.x < 32) bins[threadIdx.x] = 0;
}

__global__ void k_hist(const int* __restrict__ len, int* __restrict__ bins) {
    int p = blockIdx.x * 256 + threadIdx.x;
    if (p < PPP) atomicAdd(&bins[len[p] - 1], 1);
}

__global__ void k_scan(const int* __restrict__ bins, int* __restrict__ cur) {
    if (threadIdx.x == 0 && blockIdx.x == 0) {
        int ofs = 0;
        for (int l = 0; l < TT; l++) { cur[l] = ofs; ofs += bins[l]; }
    }
}

__global__ void k_scatter(const int* __restrict__ len, int* __restrict__ cur,
                          int* __restrict__ order) {
    int p = blockIdx.x * 256 + threadIdx.x;
    if (p < PPP) {
        int pos = atomicAdd(&cur[len[p] - 1], 1);
        order[pos] = p;
    }
}

// ---------------- precompute Zx = emb @ W + b  (per direction) --------------
// grid (VNT/8, 2). block 256: 8 tokens x 512 cols. thread: 1 token x 16 cols.

__global__ __launch_bounds__(256) void zx_kernel(
    const float* __restrict__ emb,
    const float* __restrict__ Wf, const float* __restrict__ bf,
    const float* __restrict__ Wb, const float* __restrict__ bb,
    float* __restrict__ Zall)
{
    const int dir = blockIdx.y;
    const float* W = dir ? Wb : Wf;
    const float* b = dir ? bb : bf;
    float* Z = Zall + (size_t)dir * VNT * 512;

    __shared__ float X[8][128];
    const int tid = threadIdx.x;
    const int tok0 = blockIdx.x * 8;

    // stage 8 token embeddings
    {
        int tr = tid >> 5;          // 0..7
        int c4 = (tid & 31) * 4;
        *(float4*)&X[tr][c4] = *(const float4*)(emb + (size_t)(tok0 + tr) * 128 + c4);
    }
    __syncthreads();

    const int pp = tid >> 5;        // token 0..7
    const int cg = tid & 31;        // col group: cols cg*16 .. +15
    const int c0 = cg * 16;

    float acc[16];
#pragma unroll
    for (int j = 0; j < 16; j++) acc[j] = 0.f;

    for (int k = 0; k < 128; k++) {
        float a = X[pp][k];
        const float* wr = W + (size_t)k * 512 + c0;
#pragma unroll
        for (int q = 0; q < 4; q++) {
            float4 w = *(const float4*)(wr + q * 4);
            acc[q * 4 + 0] = fmaf(a, w.x, acc[q * 4 + 0]);
            acc[q * 4 + 1] = fmaf(a, w.y, acc[q * 4 + 1]);
            acc[q * 4 + 2] = fmaf(a, w.z, acc[q * 4 + 2]);
            acc[q * 4 + 3] = fmaf(a, w.w, acc[q * 4 + 3]);
        }
    }

    float* dst = Z + (size_t)(tok0 + pp) * 512 + c0;
#pragma unroll
    for (int q = 0; q < 4; q++) {
        float4 bv = *(const float4*)(b + c0 + q * 4);
        float4 o;
        o.x = acc[q * 4 + 0] + bv.x;
        o.y = acc[q * 4 + 1] + bv.y;
        o.z = acc[q * 4 + 2] + bv.z;
        o.w = acc[q * 4 + 3] + bv.w;
        *(float4*)(dst + q * 4) = o;
    }
}

// ---------------- LSTM: z = Zx[token] + h @ U ------------------------------
// Block: 32 paths, 256 threads. Thread (tp=tid&7 -> 4 paths, tc=tid>>3 -> 4
// cols per gate). acc = float4 acc[4 gates][4 paths] (components = 4 cols).
// LDS: HT[128][36] (h, col-major, padded), Ut[2][8][512] double-buffered.

__device__ __forceinline__ float fsigmoid(float x) {
    return 1.f / (1.f + __expf(-x));
}
__device__ __forceinline__ float ftanh(float x) {
    return 2.f / (1.f + __expf(-2.f * x)) - 1.f;
}

typedef const __attribute__((address_space(1))) void GVoid;
typedef __attribute__((address_space(3))) void LVoid;

__device__ __forceinline__ void prefetch_tile(const float* __restrict__ U, int kt,
                                              float* dst, int tid) {
    // copy 16 KB (8 rows x 512 floats) contiguous, 16B per lane per round
    const char* src = (const char*)(U + (size_t)kt * 4096);
    const int wv = tid >> 6;
    const int ln = tid & 63;
#pragma unroll
    for (int j = 0; j < 4; j++) {
        int chunkbase = j * 256 + wv * 64;            // wave-uniform, 16B units
        __builtin_amdgcn_global_load_lds(
            (GVoid*)(src + (size_t)(chunkbase + ln) * 16),
            (LVoid*)((char*)dst + (size_t)chunkbase * 16),
            16, 0, 0);
    }
}

__global__ __launch_bounds__(256) void lstm_kernel(
    const float* __restrict__ Zall,
    const float* __restrict__ Uf, const float* __restrict__ Ub,
    const int* __restrict__ path_elements, const int* __restrict__ path_lengths,
    const int* __restrict__ order,
    float* __restrict__ h_out)   // [2][P][128]
{
    const int dir = blockIdx.y;
    const float* Z = Zall + (size_t)dir * VNT * 512;
    const float* U = dir ? Ub : Uf;

    __shared__ float HT[128][36];     // [col][path], padded
    __shared__ float Ut[2][8][512];
    __shared__ int s_pid[PB];
    __shared__ int s_len[PB];

    const int tid = threadIdx.x;
    const int tp = tid & 7;            // path group: paths tp*4 .. +3
    const int tc = tid >> 3;           // col group: cols tc*4 .. +3 (per gate)
    const int p0 = tp * 4;
    const int c0 = tc * 4;

    if (tid < PB) {
        int pid = order[blockIdx.x * PB + tid];
        s_pid[tid] = pid;
        s_len[tid] = path_lengths[pid];
    }
    for (int i = tid; i < 128 * 36; i += 256) ((float*)HT)[i] = 0.f;
    prefetch_tile(U, 0, &Ut[0][0][0], tid);
    __syncthreads();

    const int maxLen = s_len[PB - 1];   // paths sorted ascending by length

    float4 c4[4];                       // [p], components = 4 cols
#pragma unroll
    for (int p = 0; p < 4; p++) c4[p] = make_float4(0.f, 0.f, 0.f, 0.f);

    int pidLocal[4], lenLocal[4];
#pragma unroll
    for (int p = 0; p < 4; p++) {
        pidLocal[p] = s_pid[p0 + p];
        lenLocal[p] = s_len[p0 + p];
    }
    // note: s_pid/s_len read after barrier above

    for (int step = 0; step < maxLen; step++) {
        const int t = dir ? (maxLen - 1 - step) : step;

        // acc init = Zx[token] gather (16 x float4, L2/L3 resident)
        float4 acc[4][4];                // [gate][path]
#pragma unroll
        for (int p = 0; p < 4; p++) {
            int tok = path_elements[(size_t)pidLocal[p] * TT + t];
            const float* zr = Z + (size_t)tok * 512 + c0;
#pragma unroll
            for (int g = 0; g < 4; g++)
                acc[g][p] = *(const float4*)(zr + g * 128);
        }

        // h @ U over 16 double-buffered k-tiles
        for (int kt = 0; kt < 16; kt++) {
            __syncthreads();   // tile kt arrived; other buffer free
            prefetch_tile(U, (kt + 1) & 15, &Ut[(kt + 1) & 1][0][0], tid);
            const float(*UT)[512] = Ut[kt & 1];
            const int kbase = kt * 8;
#pragma unroll
            for (int kk = 0; kk < 8; kk++) {
                float4 av = *(const float4*)&HT[kbase + kk][p0];
                float ap[4] = {av.x, av.y, av.z, av.w};
                float4 w[4];
#pragma unroll
                for (int g = 0; g < 4; g++)
                    w[g] = *(const float4*)&UT[kk][g * 128 + c0];
#pragma unroll
                for (int g = 0; g < 4; g++)
#pragma unroll
                    for (int p = 0; p < 4; p++) {
                        acc[g][p].x = fmaf(ap[p], w[g].x, acc[g][p].x);
                        acc[g][p].y = fmaf(ap[p], w[g].y, acc[g][p].y);
                        acc[g][p].z = fmaf(ap[p], w[g].z, acc[g][p].z);
                        acc[g][p].w = fmaf(ap[p], w[g].w, acc[g][p].w);
                    }
            }
        }
        __syncthreads();   // all HT reads done before gating writes

        // gating
#pragma unroll
        for (int p = 0; p < 4; p++) {
            bool valid = t < lenLocal[p];
            float zi[4] = {acc[0][p].x, acc[0][p].y, acc[0][p].z, acc[0][p].w};
            float zf[4] = {acc[1][p].x, acc[1][p].y, acc[1][p].z, acc[1][p].w};
            float zg[4] = {acc[2][p].x, acc[2][p].y, acc[2][p].z, acc[2][p].w};
            float zo[4] = {acc[3][p].x, acc[3][p].y, acc[3][p].z, acc[3][p].w};
            float* cp = &c4[p].x;
#pragma unroll
            for (int e = 0; e < 4; e++) {
                float ig = fsigmoid(zi[e]);
                float fg = fsigmoid(zf[e]);
                float gg = ftanh(zg[e]);
                float og = fsigmoid(zo[e]);
                float cn = fg * cp[e] + ig * gg;
                float hn = og * ftanh(cn);
                if (valid) {
                    cp[e] = cn;
                    HT[c0 + e][p0 + p] = hn;
                }
            }
        }
        // next step's kt=0 barrier makes gating writes visible
    }

    __syncthreads();
    // write final h: thread -> path pg, cols ch*16..+15
    {
        const int pg = tid >> 3;       // 0..31
        const int ch = tid & 7;        // 0..7
        float* dst = h_out + ((size_t)dir * PPP + s_pid[pg]) * 128 + ch * 16;
        float v[16];
#pragma unroll
        for (int j = 0; j < 16; j++) v[j] = HT[ch * 16 + j][pg];
#pragma unroll
        for (int q = 0; q < 4; q++)
            *(float4*)(dst + q * 4) = make_float4(v[q * 4 + 0], v[q * 4 + 1],
                                                  v[q * 4 + 2], v[q * 4 + 3]);
    }
}

// ---------------- projection + attention scores ----------------------------

__global__ __launch_bounds__(256) void proj_kernel(
    const float* __restrict__ leaf, const float* __restrict__ hbuf,
    const float* __restrict__ proj, const float* __restrict__ att,
    const int* __restrict__ leaf_idxs,
    float* __restrict__ full, float* __restrict__ scores)
{
    __shared__ float V[16][388];
    const int tid = threadIdx.x;
    const int p0 = blockIdx.x * 16;

    for (int idx = tid; idx < 16 * 96; idx += 256) {
        int p = idx / 96, off = idx % 96;
        const float* src;
        if (off < 16) {
            int l0 = leaf_idxs[(p0 + p) * 2 + 0];
            src = leaf + (size_t)l0 * 64 + off * 4;
        } else if (off < 32) {
            int l1 = leaf_idxs[(p0 + p) * 2 + 1];
            src = leaf + (size_t)l1 * 64 + (off - 16) * 4;
        } else if (off < 64) {
            src = hbuf + (size_t)(p0 + p) * 128 + (off - 32) * 4;
        } else {
            src = hbuf + ((size_t)PPP + p0 + p) * 128 + (off - 64) * 4;
        }
        *(float4*)&V[p][off * 4] = *(const float4*)src;
    }
    __syncthreads();

    const int pp = tid >> 4;
    const int cg = tid & 15;
    const int c0 = cg * 8;

    float acc[8];
#pragma unroll
    for (int j = 0; j < 8; j++) acc[j] = 0.f;

#pragma unroll 4
    for (int k = 0; k < 384; k++) {
        float a = V[pp][k];
        float4 w0 = *(const float4*)(proj + (size_t)k * 128 + c0);
        float4 w1 = *(const float4*)(proj + (size_t)k * 128 + c0 + 4);
        acc[0] = fmaf(a, w0.x, acc[0]);
        acc[1] = fmaf(a, w0.y, acc[1]);
        acc[2] = fmaf(a, w0.z, acc[2]);
        acc[3] = fmaf(a, w0.w, acc[3]);
        acc[4] = fmaf(a, w1.x, acc[4]);
        acc[5] = fmaf(a, w1.y, acc[5]);
        acc[6] = fmaf(a, w1.z, acc[6]);
        acc[7] = fmaf(a, w1.w, acc[7]);
    }

    float* fdst = full + (size_t)(p0 + pp) * 128 + c0;
    *(float4*)fdst = make_float4(acc[0], acc[1], acc[2], acc[3]);
    *(float4*)(fdst + 4) = make_float4(acc[4], acc[5], acc[6], acc[7]);

    float sp = 0.f;
#pragma unroll
    for (int j = 0; j < 8; j++) sp += acc[j] * att[c0 + j];
#pragma unroll
    for (int off = 8; off > 0; off >>= 1) sp += __shfl_down(sp, off, 16);
    if (cg == 0) scores[p0 + pp] = sp;
}

// ---------------- segment softmax + weighted sum ---------------------------

__global__ __launch_bounds__(128) void seg_kernel(
    const float* __restrict__ scores, const float* __restrict__ full,
    const int* __restrict__ seg, float* __restrict__ out)
{
    const int s = blockIdx.x;
    const int tid = threadIdx.x;

    int lo = 0, hi = PPP;
    while (lo < hi) { int mid = (lo + hi) >> 1; if (seg[mid] < s) lo = mid + 1; else hi = mid; }
    const int start = lo;
    lo = start; hi = PPP;
    while (lo < hi) { int mid = (lo + hi) >> 1; if (seg[mid] < s + 1) lo = mid + 1; else hi = mid; }
    const int end = lo;

    if (start >= end) { out[(size_t)s * 128 + tid] = 0.f; return; }

    __shared__ float red[128];

    float mx = -1e30f;
    for (int i = start + tid; i < end; i += 128) mx = fmaxf(mx, scores[i]);
    red[tid] = mx; __syncthreads();
    for (int off = 64; off > 0; off >>= 1) {
        if (tid < off) red[tid] = fmaxf(red[tid], red[tid + off]);
        __syncthreads();
    }
    mx = red[0]; __syncthreads();

    float den = 0.f;
    for (int i = start + tid; i < end; i += 128) den += __expf(scores[i] - mx);
    red[tid] = den; __syncthreads();
    for (int off = 64; off > 0; off >>= 1) {
        if (tid < off) red[tid] += red[tid + off];
        __syncthreads();
    }
    den = red[0];

    float acc = 0.f;
    for (int i = start; i < end; i++)
        acc = fmaf(__expf(scores[i] - mx), full[(size_t)i * 128 + tid], acc);
    out[(size_t)s * 128 + tid] = acc / den;
}

// ---------------- launch ---------------------------------------------------

extern "C" void kernel_launch(void* const* d_in, const int* in_sizes, int n_in,
                              void* d_out, int out_size, void* d_ws, size_t ws_size,
                              hipStream_t stream) {
    (void)in_sizes; (void)n_in; (void)out_size; (void)ws_size;

    const float* leaf = (const float*)d_in[0];
    const float* emb  = (const float*)d_in[1];
    const float* Wf   = (const float*)d_in[2];
    const float* Uf   = (const float*)d_in[3];
    const float* bf   = (const float*)d_in[4];
    const float* Wb   = (const float*)d_in[5];
    const float* Ub   = (const float*)d_in[6];
    const float* bb   = (const float*)d_in[7];
    const float* proj = (const float*)d_in[8];
    const float* att  = (const float*)d_in[9];
    const int* path_elements = (const int*)d_in[10];
    const int* path_lengths  = (const int*)d_in[11];
    const int* leaf_idxs     = (const int*)d_in[12];
    const int* seg           = (const int*)d_in[13];
    float* out = (float*)d_out;

    char* ws = (char*)d_ws;
    int*   order  = (int*)ws;                       // P ints = 80000 B
    int*   bins   = (int*)(ws + 80128);
    int*   cur    = (int*)(ws + 80384);
    float* Zall   = (float*)(ws + 81920);           // 2*VNT*512 f32 = 40,960,000 B
    float* hbuf   = (float*)(ws + 41041920);        // 2*P*128 f32 = 20,480,000 B
    float* full   = (float*)(ws + 61521920);        // P*128 f32 = 10,240,000 B
    float* scores = (float*)(ws + 71761920);        // P f32

    k_zero<<<1, 64, 0, stream>>>(bins);
    k_hist<<<(PPP + 255) / 256, 256, 0, stream>>>(path_lengths, bins);
    k_scan<<<1, 64, 0, stream>>>(bins, cur);
    k_scatter<<<(PPP + 255) / 256, 256, 0, stream>>>(path_lengths, cur, order);

    dim3 gz(VNT / 8, 2);
    zx_kernel<<<gz, 256, 0, stream>>>(emb, Wf, bf, Wb, bb, Zall);

    dim3 g(PPP / PB, 2);
    lstm_kernel<<<g, 256, 0, stream>>>(Zall, Uf, Ub, path_elements, path_lengths,
                                       order, hbuf);

    proj_kernel<<<PPP / 16, 256, 0, stream>>>(leaf, hbuf, proj, att, leaf_idxs,
                                              full, scores);

    seg_kernel<<<SS, 128, 0, stream>>>(scores, full, seg, out);
}